// Round 11
// baseline (361.151 us; speedup 1.0000x reference)
//
#include <hip/hip_runtime.h>

#define N_NODES 100000
#define F_IN 128
#define H1 64
#define H2 32
#define NCLS 10

#define BS_N 256                                   // nodes per bucket
#define NBUCK ((N_NODES + BS_N - 1) / BS_N)        // 391 buckets
#define LCAP 32                                    // LDS slots per bucket
#define MCAP 12288                                 // main entries/bucket incl. sentinel pad
                                                   // (8192 edges + ~1920 pad mean, +19 sigma)
#define OVCAP 2048                                 // hard-overflow entries per bucket (~never used)
#define STCAP 12288                                // build LDS stage
#define BIN_WG 256                                 // bin workgroups (1/CU), 512 thr each
#define SENT 0xFFFFFFFFu                           // sentinel entry (skipped in build)

__device__ __forceinline__ unsigned short f2bf(float f) {   // RNE f32->bf16
    unsigned int u = __float_as_uint(f);
    return (unsigned short)((u + 0x7fffu + ((u >> 16) & 1u)) >> 16);
}
// accumulate 2 packed bf16 (one dword) into a[0],a[1] — shift/and only, no cvt
__device__ __forceinline__ void accp(float* a, unsigned int u) {
    a[0] += __uint_as_float(u << 16);
    a[1] += __uint_as_float(u & 0xffff0000u);
}
__device__ __forceinline__ void accp4(float* a, uint4 v) {
    accp(a + 0, v.x); accp(a + 2, v.y); accp(a + 4, v.z); accp(a + 6, v.w);
}

// ---------------------------------------------------------------- pass 1: LDS-staged binning
// Scattered-line-op ceiling (~20-40 ops/ns) -> every global write is a full 64B line:
// batch flushes are 16-aligned chunks; final remainders are sentinel-padded to 16.
__global__ __launch_bounds__(512) void bin_kernel(const int* __restrict__ src,
                                                  const int* __restrict__ dst, int E,
                                                  unsigned int* __restrict__ gcur,
                                                  unsigned int* __restrict__ mainr,
                                                  unsigned int* __restrict__ ovcnt,
                                                  unsigned int* __restrict__ ovbuf) {
    __shared__ unsigned int buf[NBUCK][LCAP];   // 50.0 KB
    __shared__ int cnt[NBUCK];
    int tid = threadIdx.x;
    for (int b = tid; b < NBUCK; b += 512) cnt[b] = 0;

    int chunk = (E + gridDim.x - 1) / gridDim.x;
    int e_lo = blockIdx.x * chunk;
    int e_hi = min(e_lo + chunk, E);

    int d0 = 0, s0 = 0, d1 = 0, s1 = 0;
    {
        int ea = e_lo + tid, eb = e_lo + 512 + tid;
        if (ea < e_hi) { d0 = dst[ea]; s0 = src[ea]; }
        if (eb < e_hi) { d1 = dst[eb]; s1 = src[eb]; }
    }
    __syncthreads();

    for (int base = e_lo; base < e_hi; base += 1024) {
        if (base + tid < e_hi) {
            int b = d0 >> 8;
            unsigned int en = ((unsigned int)s0 << 8) | (unsigned int)(d0 & 255);
            int p = atomicAdd(&cnt[b], 1);
            if (p < LCAP) buf[b][p] = en;
            else {  // hard overflow: ~never (cnt<31 between flushes)
                unsigned int op = atomicAdd(&ovcnt[b * 16], 1u);
                if (op < OVCAP) ovbuf[(size_t)b * OVCAP + op] = en;
            }
        }
        if (base + 512 + tid < e_hi) {
            int b = d1 >> 8;
            unsigned int en = ((unsigned int)s1 << 8) | (unsigned int)(d1 & 255);
            int p = atomicAdd(&cnt[b], 1);
            if (p < LCAP) buf[b][p] = en;
            else {
                unsigned int op = atomicAdd(&ovcnt[b * 16], 1u);
                if (op < OVCAP) ovbuf[(size_t)b * OVCAP + op] = en;
            }
        }
        __syncthreads();
        {   // prefetch next batch (in flight across the flush phase)
            int nb = base + 1024;
            int ea = nb + tid, eb = nb + 512 + tid;
            if (ea < e_hi) { d0 = dst[ea]; s0 = src[ea]; }
            if (eb < e_hi) { d1 = dst[eb]; s1 = src[eb]; }
        }
        for (int b = tid; b < NBUCK; b += 512) {
            int c = cnt[b]; if (c > LCAP) c = LCAP;
            int nf = c & ~15;
            if (nf) {
                unsigned int gb = atomicAdd(&gcur[b * 16], (unsigned int)nf);
                if (gb + (unsigned)nf <= MCAP) {
                    for (int k = 0; k < nf; k += 4) {
                        uint4 v = make_uint4(buf[b][k], buf[b][k + 1],
                                             buf[b][k + 2], buf[b][k + 3]);
                        *(uint4*)&mainr[(size_t)b * MCAP + gb + k] = v;
                    }
                } else {
                    unsigned int op = atomicAdd(&ovcnt[b * 16], (unsigned int)nf);
                    for (int k = 0; k < nf; ++k)
                        if (op + k < OVCAP) ovbuf[(size_t)b * OVCAP + op + k] = buf[b][k];
                }
                int rem = c - nf;
                for (int k = 0; k < rem; ++k) buf[b][k] = buf[b][nf + k];
                cnt[b] = rem;
            } else {
                cnt[b] = c;
            }
        }
        __syncthreads();
    }
    // final flush: pad remainders (<=15) to a full 16-chunk with sentinels -> full-line stores
    for (int b = tid; b < NBUCK; b += 512) {
        int c = cnt[b]; if (c > LCAP) c = LCAP;
        if (c) {
            int cp = (c + 15) & ~15;                    // == 16 here
            for (int k = c; k < cp; ++k) buf[b][k] = SENT;
            unsigned int gb = atomicAdd(&gcur[b * 16], (unsigned int)cp);
            if (gb + (unsigned)cp <= MCAP) {
                for (int k = 0; k < cp; k += 4) {
                    uint4 v = make_uint4(buf[b][k], buf[b][k + 1],
                                         buf[b][k + 2], buf[b][k + 3]);
                    *(uint4*)&mainr[(size_t)b * MCAP + gb + k] = v;
                }
            } else {
                unsigned int op = atomicAdd(&ovcnt[b * 16], (unsigned int)c);
                for (int k = 0; k < c; ++k)
                    if (op + k < OVCAP) ovbuf[(size_t)b * OVCAP + op + k] = buf[b][k];
            }
        }
    }
}

// ---------------------------------------------------------------- pass 2: per-bucket local CSR build
__global__ __launch_bounds__(256) void build_kernel(const unsigned int* __restrict__ gcur,
                                                    unsigned int* __restrict__ mainr,
                                                    const unsigned int* __restrict__ ovcnt,
                                                    const unsigned int* __restrict__ ovbuf,
                                                    float* __restrict__ dinv,
                                                    int* __restrict__ row_start,
                                                    int* __restrict__ row_end) {
    __shared__ unsigned int stage[STCAP];   // 48 KB
    __shared__ int degl[BS_N];
    __shared__ int rs_l[BS_N];
    __shared__ int curl[BS_N];
    __shared__ int wtot[4];
    int b = blockIdx.x;
    int tid = threadIdx.x;

    int cm = (int)gcur[b * 16]; if (cm > MCAP) cm = MCAP;
    for (int i = tid; i < cm; i += 256) stage[i] = mainr[(size_t)b * MCAP + i];
    int co = (int)ovcnt[b * 16]; if (co > OVCAP) co = OVCAP;
    for (int i = tid; i < co; i += 256) {
        int p = cm + i;
        if (p < STCAP) stage[p] = ovbuf[(size_t)b * OVCAP + i];
    }
    int c = cm + co; if (c > STCAP) c = STCAP;
    degl[tid] = 0;
    __syncthreads();

    for (int i = tid; i < c; i += 256) {
        unsigned int en = stage[i];
        if (en != SENT) atomicAdd(&degl[en & 255], 1);
    }
    __syncthreads();

    int lane = tid & 63, w = tid >> 6;
    int d = degl[tid];
    int x = d;
    #pragma unroll
    for (int off = 1; off < 64; off <<= 1) {
        int y = __shfl_up(x, off);
        if (lane >= off) x += y;
    }
    if (lane == 63) wtot[w] = x;
    __syncthreads();
    int pbase = 0;
    #pragma unroll
    for (int k = 0; k < 4; ++k) if (k < w) pbase += wtot[k];
    rs_l[tid] = pbase + x - d;
    curl[tid] = 0;
    __syncthreads();

    size_t gbase = (size_t)b * MCAP;
    for (int i = tid; i < c; i += 256) {
        unsigned int en = stage[i];
        if (en != SENT) {
            int dl = en & 255;
            int p = atomicAdd(&curl[dl], 1);
            mainr[gbase + rs_l[dl] + p] = en >> 8;
        }
    }
    int node = b * BS_N + tid;
    if (node < N_NODES) {
        int deg = degl[tid];
        dinv[node] = rsqrtf((float)deg + 1.0f);
        row_start[node] = (int)gbase + rs_l[tid];
        row_end[node] = (int)gbase + rs_l[tid] + deg;
    }
}

// ---------------------------------------------------------------- GEMM 1: [N,128]@[128,64] -> bf16, scaled by dinv
__global__ __launch_bounds__(256) void gemm1_kernel(const float* __restrict__ X,
                                                    const float* __restrict__ W,
                                                    const float* __restrict__ dinv,
                                                    unsigned short* __restrict__ H) {
    __shared__ float Xs[64][68];
    __shared__ float Ws[F_IN * H1];
    int r0 = blockIdx.x * 64;
    const float4* W4 = (const float4*)W;
    float4* Ws4 = (float4*)Ws;
    for (int i = threadIdx.x; i < F_IN * H1 / 4; i += 256) Ws4[i] = W4[i];

    int tx = threadIdx.x & 15;
    int ty = threadIdx.x >> 4;
    float acc[4][4] = {};

    for (int kh = 0; kh < 2; ++kh) {
        __syncthreads();
        for (int it = 0; it < 4; ++it) {
            int idx = threadIdx.x + it * 256;
            int r = idx >> 4, k4 = idx & 15;
            int row = r0 + r;
            float4 v = (row < N_NODES)
                ? ((const float4*)X)[(size_t)row * 32 + kh * 16 + k4]
                : make_float4(0.f, 0.f, 0.f, 0.f);
            *(float4*)&Xs[r][k4 * 4] = v;
        }
        __syncthreads();
        #pragma unroll 8
        for (int k = 0; k < 64; ++k) {
            float4 wb = *(const float4*)&Ws[(kh * 64 + k) * H1 + tx * 4];
            float xa0 = Xs[ty * 4 + 0][k];
            float xa1 = Xs[ty * 4 + 1][k];
            float xa2 = Xs[ty * 4 + 2][k];
            float xa3 = Xs[ty * 4 + 3][k];
            acc[0][0] += xa0 * wb.x; acc[0][1] += xa0 * wb.y; acc[0][2] += xa0 * wb.z; acc[0][3] += xa0 * wb.w;
            acc[1][0] += xa1 * wb.x; acc[1][1] += xa1 * wb.y; acc[1][2] += xa1 * wb.z; acc[1][3] += xa1 * wb.w;
            acc[2][0] += xa2 * wb.x; acc[2][1] += xa2 * wb.y; acc[2][2] += xa2 * wb.z; acc[2][3] += xa2 * wb.w;
            acc[3][0] += xa3 * wb.x; acc[3][1] += xa3 * wb.y; acc[3][2] += xa3 * wb.z; acc[3][3] += xa3 * wb.w;
        }
    }
    #pragma unroll
    for (int i = 0; i < 4; ++i) {
        int row = r0 + ty * 4 + i;
        if (row < N_NODES) {
            float dv = dinv[row];
            unsigned int lo = (unsigned int)f2bf(acc[i][0] * dv) |
                              ((unsigned int)f2bf(acc[i][1] * dv) << 16);
            unsigned int hi = (unsigned int)f2bf(acc[i][2] * dv) |
                              ((unsigned int)f2bf(acc[i][3] * dv) << 16);
            *(uint2*)&H[(size_t)row * H1 + tx * 4] = make_uint2(lo, hi);
        }
    }
}

// ---------------------------------------------------------------- GEMM 2: [N,64]@[64,32] -> bf16, scaled by dinv
__global__ __launch_bounds__(256) void gemm2_kernel(const float* __restrict__ X,
                                                    const float* __restrict__ W,
                                                    const float* __restrict__ dinv,
                                                    unsigned short* __restrict__ H) {
    __shared__ float Xs[64][68];
    __shared__ float Ws[H1 * H2];
    int r0 = blockIdx.x * 64;
    const float4* W4 = (const float4*)W;
    float4* Ws4 = (float4*)Ws;
    for (int i = threadIdx.x; i < H1 * H2 / 4; i += 256) Ws4[i] = W4[i];
    for (int it = 0; it < 4; ++it) {
        int idx = threadIdx.x + it * 256;
        int r = idx >> 4, k4 = idx & 15;
        int row = r0 + r;
        float4 v = (row < N_NODES)
            ? ((const float4*)X)[(size_t)row * 16 + k4]
            : make_float4(0.f, 0.f, 0.f, 0.f);
        *(float4*)&Xs[r][k4 * 4] = v;
    }
    __syncthreads();
    int tx = threadIdx.x & 15;
    int ty = threadIdx.x >> 4;
    float acc[4][2] = {};
    #pragma unroll 8
    for (int k = 0; k < 64; ++k) {
        float2 wb = *(const float2*)&Ws[k * H2 + tx * 2];
        float xa0 = Xs[ty * 4 + 0][k];
        float xa1 = Xs[ty * 4 + 1][k];
        float xa2 = Xs[ty * 4 + 2][k];
        float xa3 = Xs[ty * 4 + 3][k];
        acc[0][0] += xa0 * wb.x; acc[0][1] += xa0 * wb.y;
        acc[1][0] += xa1 * wb.x; acc[1][1] += xa1 * wb.y;
        acc[2][0] += xa2 * wb.x; acc[2][1] += xa2 * wb.y;
        acc[3][0] += xa3 * wb.x; acc[3][1] += xa3 * wb.y;
    }
    #pragma unroll
    for (int i = 0; i < 4; ++i) {
        int row = r0 + ty * 4 + i;
        if (row < N_NODES) {
            float dv = dinv[row];
            unsigned int v = (unsigned int)f2bf(acc[i][0] * dv) |
                             ((unsigned int)f2bf(acc[i][1] * dv) << 16);
            *(unsigned int*)&H[(size_t)row * H2 + tx * 2] = v;
        }
    }
}

// ---------------------------------------------------------------- pull1: wave/node, 8 lanes/edge, uint4 gathers
__global__ __launch_bounds__(256) void pull1_kernel(const unsigned short* __restrict__ h,
                                                    const unsigned int* __restrict__ csr,
                                                    const int* __restrict__ row_start,
                                                    const int* __restrict__ row_end,
                                                    const float* __restrict__ dinv,
                                                    const float* __restrict__ b,
                                                    float* __restrict__ xout) {
    int wave = (blockIdx.x * 256 + threadIdx.x) >> 6;   // grid exact: 25000 blocks
    int lane = threadIdx.x & 63;
    int g = lane >> 3;
    int sub = lane & 7;
    int i = wave;
    int e0 = row_start[i], e1 = row_end[i];
    float acc[8] = {};
    int e = e0;
    for (; e + 16 <= e1; e += 16) {
        int s0 = csr[e + g];
        int s1 = csr[e + 8 + g];
        uint4 v0 = *(const uint4*)&h[(size_t)s0 * H1 + sub * 8];
        uint4 v1 = *(const uint4*)&h[(size_t)s1 * H1 + sub * 8];
        accp4(acc, v0);
        accp4(acc, v1);
    }
    if (e + 8 <= e1) {
        int s = csr[e + g];
        uint4 v = *(const uint4*)&h[(size_t)s * H1 + sub * 8];
        accp4(acc, v);
        e += 8;
    }
    if (e < e1) {
        int idx = e + g;
        if (idx < e1) {
            int s = csr[idx];
            uint4 v = *(const uint4*)&h[(size_t)s * H1 + sub * 8];
            accp4(acc, v);
        }
    }
    #pragma unroll
    for (int m = 8; m < 64; m <<= 1) {
        #pragma unroll
        for (int j = 0; j < 8; ++j) acc[j] += __shfl_xor(acc[j], m);
    }
    if (g == 0) {
        float di = dinv[i];
        uint4 sv = *(const uint4*)&h[(size_t)i * H1 + sub * 8];   // self loop
        accp4(acc, sv);
        float4 o0, o1;
        o0.x = fmaxf(di * acc[0] + b[sub * 8 + 0], 0.0f);
        o0.y = fmaxf(di * acc[1] + b[sub * 8 + 1], 0.0f);
        o0.z = fmaxf(di * acc[2] + b[sub * 8 + 2], 0.0f);
        o0.w = fmaxf(di * acc[3] + b[sub * 8 + 3], 0.0f);
        o1.x = fmaxf(di * acc[4] + b[sub * 8 + 4], 0.0f);
        o1.y = fmaxf(di * acc[5] + b[sub * 8 + 5], 0.0f);
        o1.z = fmaxf(di * acc[6] + b[sub * 8 + 6], 0.0f);
        o1.w = fmaxf(di * acc[7] + b[sub * 8 + 7], 0.0f);
        *(float4*)&xout[(size_t)i * H1 + sub * 8] = o0;
        *(float4*)&xout[(size_t)i * H1 + sub * 8 + 4] = o1;
    }
}

// ---------------------------------------------------------------- pull2 fused with classifier+log_softmax
// wave/node, 4 lanes/edge gathers; butterfly leaves FULL sums in ALL lanes ->
// in-wave GEMV (shuffle-broadcast x2, Wc from LDS) -> 16-lane log_softmax -> write out.
__global__ __launch_bounds__(256) void pull2_kernel(const unsigned short* __restrict__ h,
                                                    const unsigned int* __restrict__ csr,
                                                    const int* __restrict__ row_start,
                                                    const int* __restrict__ row_end,
                                                    const float* __restrict__ dinv,
                                                    const float* __restrict__ b2,
                                                    const float* __restrict__ Wc,
                                                    const float* __restrict__ bc,
                                                    float* __restrict__ out) {
    __shared__ float Wcs[336];   // 320 used; 336 > 256 threads: MUST stride-loop (R1/R10 bug!)
    __shared__ float b2s[32];
    __shared__ float bcs[16];
    for (int t = threadIdx.x; t < 336; t += 256)
        Wcs[t] = (t < H2 * NCLS) ? Wc[t] : 0.0f;
    {
        int t = threadIdx.x;
        if (t < 32) b2s[t] = b2[t];
        if (t < 16) bcs[t] = (t < NCLS) ? bc[t] : 0.0f;
    }
    __syncthreads();

    int wave = (blockIdx.x * 256 + threadIdx.x) >> 6;
    int lane = threadIdx.x & 63;
    int g = lane >> 2;
    int sub = lane & 3;
    int i = wave;
    int e0 = row_start[i], e1 = row_end[i];
    float acc[8] = {};
    int e = e0;
    for (; e + 32 <= e1; e += 32) {
        int s0 = csr[e + g];
        int s1 = csr[e + 16 + g];
        uint4 v0 = *(const uint4*)&h[(size_t)s0 * H2 + sub * 8];
        uint4 v1 = *(const uint4*)&h[(size_t)s1 * H2 + sub * 8];
        accp4(acc, v0);
        accp4(acc, v1);
    }
    if (e + 16 <= e1) {
        int s = csr[e + g];
        uint4 v = *(const uint4*)&h[(size_t)s * H2 + sub * 8];
        accp4(acc, v);
        e += 16;
    }
    if (e < e1) {
        int idx = e + g;
        if (idx < e1) {
            int s = csr[idx];
            uint4 v = *(const uint4*)&h[(size_t)s * H2 + sub * 8];
            accp4(acc, v);
        }
    }
    #pragma unroll
    for (int m = 4; m < 64; m <<= 1) {
        #pragma unroll
        for (int j = 0; j < 8; ++j) acc[j] += __shfl_xor(acc[j], m);
    }
    // x2 row (features sub*8..+7) in ALL lanes: self loop + bias + relu
    float di = dinv[i];
    uint4 sv = *(const uint4*)&h[(size_t)i * H2 + sub * 8];
    accp4(acc, sv);
    float x2v[8];
    #pragma unroll
    for (int j = 0; j < 8; ++j)
        x2v[j] = fmaxf(di * acc[j] + b2s[sub * 8 + j], 0.0f);

    // GEMV: logits; lane computes c = lane&15 (valid c<10); 4 replicated groups
    int c = lane & 15;
    float lg = bcs[c];
    #pragma unroll
    for (int k = 0; k < H2; ++k) {
        float xv = __shfl(x2v[k & 7], k >> 3);    // broadcast x2[k] from lane k>>3
        lg += xv * Wcs[k * NCLS + c];
    }
    // log_softmax over c=0..9 within each 16-lane group
    float mval = (c < NCLS) ? lg : -3.4e38f;
    #pragma unroll
    for (int m = 1; m < 16; m <<= 1) mval = fmaxf(mval, __shfl_xor(mval, m));
    float ex = (c < NCLS) ? expf(lg - mval) : 0.0f;
    #pragma unroll
    for (int m = 1; m < 16; m <<= 1) ex += __shfl_xor(ex, m);
    float o = lg - mval - logf(ex);
    if (lane < NCLS) out[(size_t)i * NCLS + lane] = o;
}

// ----------------------------------------------------------------
extern "C" void kernel_launch(void* const* d_in, const int* in_sizes, int n_in,
                              void* d_out, int out_size, void* d_ws, size_t ws_size,
                              hipStream_t stream) {
    const float* feature = (const float*)d_in[0];
    const int*   eidx    = (const int*)d_in[1];
    const float* W1      = (const float*)d_in[2];
    const float* b1      = (const float*)d_in[3];
    const float* W2      = (const float*)d_in[4];
    const float* b2      = (const float*)d_in[5];
    const float* Wc      = (const float*)d_in[6];
    const float* bc      = (const float*)d_in[7];
    float* out = (float*)d_out;

    const int E = in_sizes[1] / 2;
    const int* src = eidx;
    const int* dst = eidx + E;

    float*          ws        = (float*)d_ws;
    float*          dinv      = ws;
    int*            row_start = (int*)(dinv + N_NODES);
    int*            row_end   = row_start + N_NODES;
    unsigned int*   gcur      = (unsigned int*)(row_end + N_NODES);
    unsigned int*   ovcnt     = gcur + (size_t)NBUCK * 16;
    unsigned int*   ovbuf     = ovcnt + (size_t)NBUCK * 16;
    unsigned int*   mainr     = ovbuf + (size_t)NBUCK * OVCAP;
    unsigned short* h1b       = (unsigned short*)(mainr + (size_t)NBUCK * MCAP);
    float*          x1        = (float*)(h1b + (size_t)N_NODES * H1);
    unsigned short* h2b       = h1b;                 // overlay: h1 dead after pull1

    // CSR build
    hipMemsetAsync(gcur, 0, (size_t)NBUCK * 32 * sizeof(unsigned int), stream);
    bin_kernel<<<BIN_WG, 512, 0, stream>>>(src, dst, E, gcur, mainr, ovcnt, ovbuf);
    build_kernel<<<NBUCK, 256, 0, stream>>>(gcur, mainr, ovcnt, ovbuf,
                                            dinv, row_start, row_end);

    // layer 1
    gemm1_kernel<<<(N_NODES + 63) / 64, 256, 0, stream>>>(feature, W1, dinv, h1b);
    {
        unsigned int grid = (unsigned int)(((size_t)N_NODES * 64 + 255) / 256);
        pull1_kernel<<<grid, 256, 0, stream>>>(h1b, mainr, row_start, row_end, dinv, b1, x1);
    }

    // layer 2 + fused classifier/log_softmax
    gemm2_kernel<<<(N_NODES + 63) / 64, 256, 0, stream>>>(x1, W2, dinv, h2b);
    {
        unsigned int grid = (unsigned int)(((size_t)N_NODES * 64 + 255) / 256);
        pull2_kernel<<<grid, 256, 0, stream>>>(h2b, mainr, row_start, row_end, dinv,
                                               b2, Wc, bc, out);
    }
}

// Round 12
// 316.086 us; speedup vs baseline: 1.1426x; 1.1426x over previous
//
#include <hip/hip_runtime.h>

#define N_NODES 100000
#define F_IN 128
#define H1 64
#define H2 32
#define NCLS 10

#define BS_N 256                                   // nodes per bucket
#define NBUCK ((N_NODES + BS_N - 1) / BS_N)        // 391 buckets
#define LCAP 32                                    // LDS slots per bucket
#define MCAP 12288                                 // main entries/bucket incl. sentinel pad
#define OVCAP 2048                                 // hard-overflow entries per bucket (~never used)
#define STCAP 12288                                // build LDS stage
#define BIN_WG 256                                 // bin workgroups (1/CU), 512 thr each
#define SENT 0xFFFFFFFFu                           // sentinel entry (skipped in build)

__device__ __forceinline__ unsigned short f2bf(float f) {   // RNE f32->bf16
    unsigned int u = __float_as_uint(f);
    return (unsigned short)((u + 0x7fffu + ((u >> 16) & 1u)) >> 16);
}
// accumulate 2 packed bf16 (one dword) into a[0],a[1] — shift/and only, no cvt
__device__ __forceinline__ void accp(float* a, unsigned int u) {
    a[0] += __uint_as_float(u << 16);
    a[1] += __uint_as_float(u & 0xffff0000u);
}
__device__ __forceinline__ void accp4(float* a, uint4 v) {
    accp(a + 0, v.x); accp(a + 2, v.y); accp(a + 4, v.z); accp(a + 6, v.w);
}

// ---------------------------------------------------------------- pass 1: LDS-staged binning
// Scattered-line-op ceiling (~20-40 ops/ns) -> every global write is a full 64B line:
// batch flushes are 16-aligned chunks; final remainders are sentinel-padded to 16.
__global__ __launch_bounds__(512) void bin_kernel(const int* __restrict__ src,
                                                  const int* __restrict__ dst, int E,
                                                  unsigned int* __restrict__ gcur,
                                                  unsigned int* __restrict__ mainr,
                                                  unsigned int* __restrict__ ovcnt,
                                                  unsigned int* __restrict__ ovbuf) {
    __shared__ unsigned int buf[NBUCK][LCAP];   // 50.0 KB
    __shared__ int cnt[NBUCK];
    int tid = threadIdx.x;
    for (int b = tid; b < NBUCK; b += 512) cnt[b] = 0;

    int chunk = (E + gridDim.x - 1) / gridDim.x;
    int e_lo = blockIdx.x * chunk;
    int e_hi = min(e_lo + chunk, E);

    int d0 = 0, s0 = 0, d1 = 0, s1 = 0;
    {
        int ea = e_lo + tid, eb = e_lo + 512 + tid;
        if (ea < e_hi) { d0 = dst[ea]; s0 = src[ea]; }
        if (eb < e_hi) { d1 = dst[eb]; s1 = src[eb]; }
    }
    __syncthreads();

    for (int base = e_lo; base < e_hi; base += 1024) {
        if (base + tid < e_hi) {
            int b = d0 >> 8;
            unsigned int en = ((unsigned int)s0 << 8) | (unsigned int)(d0 & 255);
            int p = atomicAdd(&cnt[b], 1);
            if (p < LCAP) buf[b][p] = en;
            else {
                unsigned int op = atomicAdd(&ovcnt[b * 16], 1u);
                if (op < OVCAP) ovbuf[(size_t)b * OVCAP + op] = en;
            }
        }
        if (base + 512 + tid < e_hi) {
            int b = d1 >> 8;
            unsigned int en = ((unsigned int)s1 << 8) | (unsigned int)(d1 & 255);
            int p = atomicAdd(&cnt[b], 1);
            if (p < LCAP) buf[b][p] = en;
            else {
                unsigned int op = atomicAdd(&ovcnt[b * 16], 1u);
                if (op < OVCAP) ovbuf[(size_t)b * OVCAP + op] = en;
            }
        }
        __syncthreads();
        {   // prefetch next batch (in flight across the flush phase)
            int nb = base + 1024;
            int ea = nb + tid, eb = nb + 512 + tid;
            if (ea < e_hi) { d0 = dst[ea]; s0 = src[ea]; }
            if (eb < e_hi) { d1 = dst[eb]; s1 = src[eb]; }
        }
        for (int b = tid; b < NBUCK; b += 512) {
            int c = cnt[b]; if (c > LCAP) c = LCAP;
            int nf = c & ~15;
            if (nf) {
                unsigned int gb = atomicAdd(&gcur[b * 16], (unsigned int)nf);
                if (gb + (unsigned)nf <= MCAP) {
                    for (int k = 0; k < nf; k += 4) {
                        uint4 v = make_uint4(buf[b][k], buf[b][k + 1],
                                             buf[b][k + 2], buf[b][k + 3]);
                        *(uint4*)&mainr[(size_t)b * MCAP + gb + k] = v;
                    }
                } else {
                    unsigned int op = atomicAdd(&ovcnt[b * 16], (unsigned int)nf);
                    for (int k = 0; k < nf; ++k)
                        if (op + k < OVCAP) ovbuf[(size_t)b * OVCAP + op + k] = buf[b][k];
                }
                int rem = c - nf;
                for (int k = 0; k < rem; ++k) buf[b][k] = buf[b][nf + k];
                cnt[b] = rem;
            } else {
                cnt[b] = c;
            }
        }
        __syncthreads();
    }
    // final flush: pad remainders (<=15) to a full 16-chunk with sentinels -> full-line stores
    for (int b = tid; b < NBUCK; b += 512) {
        int c = cnt[b]; if (c > LCAP) c = LCAP;
        if (c) {
            int cp = (c + 15) & ~15;
            for (int k = c; k < cp; ++k) buf[b][k] = SENT;
            unsigned int gb = atomicAdd(&gcur[b * 16], (unsigned int)cp);
            if (gb + (unsigned)cp <= MCAP) {
                for (int k = 0; k < cp; k += 4) {
                    uint4 v = make_uint4(buf[b][k], buf[b][k + 1],
                                         buf[b][k + 2], buf[b][k + 3]);
                    *(uint4*)&mainr[(size_t)b * MCAP + gb + k] = v;
                }
            } else {
                unsigned int op = atomicAdd(&ovcnt[b * 16], (unsigned int)c);
                for (int k = 0; k < c; ++k)
                    if (op + k < OVCAP) ovbuf[(size_t)b * OVCAP + op + k] = buf[b][k];
            }
        }
    }
}

// ---------------------------------------------------------------- pass 2: per-bucket local CSR build
__global__ __launch_bounds__(256) void build_kernel(const unsigned int* __restrict__ gcur,
                                                    unsigned int* __restrict__ mainr,
                                                    const unsigned int* __restrict__ ovcnt,
                                                    const unsigned int* __restrict__ ovbuf,
                                                    float* __restrict__ dinv,
                                                    int* __restrict__ row_start,
                                                    int* __restrict__ row_end) {
    __shared__ unsigned int stage[STCAP];   // 48 KB
    __shared__ int degl[BS_N];
    __shared__ int rs_l[BS_N];
    __shared__ int curl[BS_N];
    __shared__ int wtot[4];
    int b = blockIdx.x;
    int tid = threadIdx.x;

    int cm = (int)gcur[b * 16]; if (cm > MCAP) cm = MCAP;
    for (int i = tid; i < cm; i += 256) stage[i] = mainr[(size_t)b * MCAP + i];
    int co = (int)ovcnt[b * 16]; if (co > OVCAP) co = OVCAP;
    for (int i = tid; i < co; i += 256) {
        int p = cm + i;
        if (p < STCAP) stage[p] = ovbuf[(size_t)b * OVCAP + i];
    }
    int c = cm + co; if (c > STCAP) c = STCAP;
    degl[tid] = 0;
    __syncthreads();

    for (int i = tid; i < c; i += 256) {
        unsigned int en = stage[i];
        if (en != SENT) atomicAdd(&degl[en & 255], 1);
    }
    __syncthreads();

    int lane = tid & 63, w = tid >> 6;
    int d = degl[tid];
    int x = d;
    #pragma unroll
    for (int off = 1; off < 64; off <<= 1) {
        int y = __shfl_up(x, off);
        if (lane >= off) x += y;
    }
    if (lane == 63) wtot[w] = x;
    __syncthreads();
    int pbase = 0;
    #pragma unroll
    for (int k = 0; k < 4; ++k) if (k < w) pbase += wtot[k];
    rs_l[tid] = pbase + x - d;
    curl[tid] = 0;
    __syncthreads();

    size_t gbase = (size_t)b * MCAP;
    for (int i = tid; i < c; i += 256) {
        unsigned int en = stage[i];
        if (en != SENT) {
            int dl = en & 255;
            int p = atomicAdd(&curl[dl], 1);
            mainr[gbase + rs_l[dl] + p] = en >> 8;
        }
    }
    int node = b * BS_N + tid;
    if (node < N_NODES) {
        int deg = degl[tid];
        dinv[node] = rsqrtf((float)deg + 1.0f);
        row_start[node] = (int)gbase + rs_l[tid];
        row_end[node] = (int)gbase + rs_l[tid] + deg;
    }
}

// ---------------------------------------------------------------- GEMM 1: [N,128]@[128,64] -> bf16, scaled by dinv
__global__ __launch_bounds__(256) void gemm1_kernel(const float* __restrict__ X,
                                                    const float* __restrict__ W,
                                                    const float* __restrict__ dinv,
                                                    unsigned short* __restrict__ H) {
    __shared__ float Xs[64][68];
    __shared__ float Ws[F_IN * H1];
    int r0 = blockIdx.x * 64;
    const float4* W4 = (const float4*)W;
    float4* Ws4 = (float4*)Ws;
    for (int i = threadIdx.x; i < F_IN * H1 / 4; i += 256) Ws4[i] = W4[i];

    int tx = threadIdx.x & 15;
    int ty = threadIdx.x >> 4;
    float acc[4][4] = {};

    for (int kh = 0; kh < 2; ++kh) {
        __syncthreads();
        for (int it = 0; it < 4; ++it) {
            int idx = threadIdx.x + it * 256;
            int r = idx >> 4, k4 = idx & 15;
            int row = r0 + r;
            float4 v = (row < N_NODES)
                ? ((const float4*)X)[(size_t)row * 32 + kh * 16 + k4]
                : make_float4(0.f, 0.f, 0.f, 0.f);
            *(float4*)&Xs[r][k4 * 4] = v;
        }
        __syncthreads();
        #pragma unroll 8
        for (int k = 0; k < 64; ++k) {
            float4 wb = *(const float4*)&Ws[(kh * 64 + k) * H1 + tx * 4];
            float xa0 = Xs[ty * 4 + 0][k];
            float xa1 = Xs[ty * 4 + 1][k];
            float xa2 = Xs[ty * 4 + 2][k];
            float xa3 = Xs[ty * 4 + 3][k];
            acc[0][0] += xa0 * wb.x; acc[0][1] += xa0 * wb.y; acc[0][2] += xa0 * wb.z; acc[0][3] += xa0 * wb.w;
            acc[1][0] += xa1 * wb.x; acc[1][1] += xa1 * wb.y; acc[1][2] += xa1 * wb.z; acc[1][3] += xa1 * wb.w;
            acc[2][0] += xa2 * wb.x; acc[2][1] += xa2 * wb.y; acc[2][2] += xa2 * wb.z; acc[2][3] += xa2 * wb.w;
            acc[3][0] += xa3 * wb.x; acc[3][1] += xa3 * wb.y; acc[3][2] += xa3 * wb.z; acc[3][3] += xa3 * wb.w;
        }
    }
    #pragma unroll
    for (int i = 0; i < 4; ++i) {
        int row = r0 + ty * 4 + i;
        if (row < N_NODES) {
            float dv = dinv[row];
            unsigned int lo = (unsigned int)f2bf(acc[i][0] * dv) |
                              ((unsigned int)f2bf(acc[i][1] * dv) << 16);
            unsigned int hi = (unsigned int)f2bf(acc[i][2] * dv) |
                              ((unsigned int)f2bf(acc[i][3] * dv) << 16);
            *(uint2*)&H[(size_t)row * H1 + tx * 4] = make_uint2(lo, hi);
        }
    }
}

// ---------------------------------------------------------------- GEMM 2: [N,64]@[64,32] -> bf16, scaled by dinv
__global__ __launch_bounds__(256) void gemm2_kernel(const float* __restrict__ X,
                                                    const float* __restrict__ W,
                                                    const float* __restrict__ dinv,
                                                    unsigned short* __restrict__ H) {
    __shared__ float Xs[64][68];
    __shared__ float Ws[H1 * H2];
    int r0 = blockIdx.x * 64;
    const float4* W4 = (const float4*)W;
    float4* Ws4 = (float4*)Ws;
    for (int i = threadIdx.x; i < H1 * H2 / 4; i += 256) Ws4[i] = W4[i];
    for (int it = 0; it < 4; ++it) {
        int idx = threadIdx.x + it * 256;
        int r = idx >> 4, k4 = idx & 15;
        int row = r0 + r;
        float4 v = (row < N_NODES)
            ? ((const float4*)X)[(size_t)row * 16 + k4]
            : make_float4(0.f, 0.f, 0.f, 0.f);
        *(float4*)&Xs[r][k4 * 4] = v;
    }
    __syncthreads();
    int tx = threadIdx.x & 15;
    int ty = threadIdx.x >> 4;
    float acc[4][2] = {};
    #pragma unroll 8
    for (int k = 0; k < 64; ++k) {
        float2 wb = *(const float2*)&Ws[k * H2 + tx * 2];
        float xa0 = Xs[ty * 4 + 0][k];
        float xa1 = Xs[ty * 4 + 1][k];
        float xa2 = Xs[ty * 4 + 2][k];
        float xa3 = Xs[ty * 4 + 3][k];
        acc[0][0] += xa0 * wb.x; acc[0][1] += xa0 * wb.y;
        acc[1][0] += xa1 * wb.x; acc[1][1] += xa1 * wb.y;
        acc[2][0] += xa2 * wb.x; acc[2][1] += xa2 * wb.y;
        acc[3][0] += xa3 * wb.x; acc[3][1] += xa3 * wb.y;
    }
    #pragma unroll
    for (int i = 0; i < 4; ++i) {
        int row = r0 + ty * 4 + i;
        if (row < N_NODES) {
            float dv = dinv[row];
            unsigned int v = (unsigned int)f2bf(acc[i][0] * dv) |
                             ((unsigned int)f2bf(acc[i][1] * dv) << 16);
            *(unsigned int*)&H[(size_t)row * H2 + tx * 2] = v;
        }
    }
}

// ---------------------------------------------------------------- pull1: wave/node, 8 lanes/edge, uint4 gathers
__global__ __launch_bounds__(256) void pull1_kernel(const unsigned short* __restrict__ h,
                                                    const unsigned int* __restrict__ csr,
                                                    const int* __restrict__ row_start,
                                                    const int* __restrict__ row_end,
                                                    const float* __restrict__ dinv,
                                                    const float* __restrict__ b,
                                                    float* __restrict__ xout) {
    int wave = (blockIdx.x * 256 + threadIdx.x) >> 6;   // grid exact: 25000 blocks
    int lane = threadIdx.x & 63;
    int g = lane >> 3;
    int sub = lane & 7;
    int i = wave;
    int e0 = row_start[i], e1 = row_end[i];
    float acc[8] = {};
    int e = e0;
    for (; e + 16 <= e1; e += 16) {
        int s0 = csr[e + g];
        int s1 = csr[e + 8 + g];
        uint4 v0 = *(const uint4*)&h[(size_t)s0 * H1 + sub * 8];
        uint4 v1 = *(const uint4*)&h[(size_t)s1 * H1 + sub * 8];
        accp4(acc, v0);
        accp4(acc, v1);
    }
    if (e + 8 <= e1) {
        int s = csr[e + g];
        uint4 v = *(const uint4*)&h[(size_t)s * H1 + sub * 8];
        accp4(acc, v);
        e += 8;
    }
    if (e < e1) {
        int idx = e + g;
        if (idx < e1) {
            int s = csr[idx];
            uint4 v = *(const uint4*)&h[(size_t)s * H1 + sub * 8];
            accp4(acc, v);
        }
    }
    #pragma unroll
    for (int m = 8; m < 64; m <<= 1) {
        #pragma unroll
        for (int j = 0; j < 8; ++j) acc[j] += __shfl_xor(acc[j], m);
    }
    if (g == 0) {
        float di = dinv[i];
        uint4 sv = *(const uint4*)&h[(size_t)i * H1 + sub * 8];   // self loop
        accp4(acc, sv);
        float4 o0, o1;
        o0.x = fmaxf(di * acc[0] + b[sub * 8 + 0], 0.0f);
        o0.y = fmaxf(di * acc[1] + b[sub * 8 + 1], 0.0f);
        o0.z = fmaxf(di * acc[2] + b[sub * 8 + 2], 0.0f);
        o0.w = fmaxf(di * acc[3] + b[sub * 8 + 3], 0.0f);
        o1.x = fmaxf(di * acc[4] + b[sub * 8 + 4], 0.0f);
        o1.y = fmaxf(di * acc[5] + b[sub * 8 + 5], 0.0f);
        o1.z = fmaxf(di * acc[6] + b[sub * 8 + 6], 0.0f);
        o1.w = fmaxf(di * acc[7] + b[sub * 8 + 7], 0.0f);
        *(float4*)&xout[(size_t)i * H1 + sub * 8] = o0;
        *(float4*)&xout[(size_t)i * H1 + sub * 8 + 4] = o1;
    }
}

// ---------------------------------------------------------------- pull2: wave/node, 4 lanes/edge, uint4 gathers
// (R9 structure — the fused-classifier variant serialized on a VGPR-starved
//  shuffle chain, +45 µs; keep the classifier as a separate kernel)
__global__ __launch_bounds__(256) void pull2_kernel(const unsigned short* __restrict__ h,
                                                    const unsigned int* __restrict__ csr,
                                                    const int* __restrict__ row_start,
                                                    const int* __restrict__ row_end,
                                                    const float* __restrict__ dinv,
                                                    const float* __restrict__ b,
                                                    float* __restrict__ xout) {
    int wave = (blockIdx.x * 256 + threadIdx.x) >> 6;
    int lane = threadIdx.x & 63;
    int g = lane >> 2;
    int sub = lane & 3;
    int i = wave;
    int e0 = row_start[i], e1 = row_end[i];
    float acc[8] = {};
    int e = e0;
    for (; e + 32 <= e1; e += 32) {
        int s0 = csr[e + g];
        int s1 = csr[e + 16 + g];
        uint4 v0 = *(const uint4*)&h[(size_t)s0 * H2 + sub * 8];
        uint4 v1 = *(const uint4*)&h[(size_t)s1 * H2 + sub * 8];
        accp4(acc, v0);
        accp4(acc, v1);
    }
    if (e + 16 <= e1) {
        int s = csr[e + g];
        uint4 v = *(const uint4*)&h[(size_t)s * H2 + sub * 8];
        accp4(acc, v);
        e += 16;
    }
    if (e < e1) {
        int idx = e + g;
        if (idx < e1) {
            int s = csr[idx];
            uint4 v = *(const uint4*)&h[(size_t)s * H2 + sub * 8];
            accp4(acc, v);
        }
    }
    #pragma unroll
    for (int m = 4; m < 64; m <<= 1) {
        #pragma unroll
        for (int j = 0; j < 8; ++j) acc[j] += __shfl_xor(acc[j], m);
    }
    if (g == 0) {
        float di = dinv[i];
        uint4 sv = *(const uint4*)&h[(size_t)i * H2 + sub * 8];   // self loop
        accp4(acc, sv);
        float4 o0, o1;
        o0.x = fmaxf(di * acc[0] + b[sub * 8 + 0], 0.0f);
        o0.y = fmaxf(di * acc[1] + b[sub * 8 + 1], 0.0f);
        o0.z = fmaxf(di * acc[2] + b[sub * 8 + 2], 0.0f);
        o0.w = fmaxf(di * acc[3] + b[sub * 8 + 3], 0.0f);
        o1.x = fmaxf(di * acc[4] + b[sub * 8 + 4], 0.0f);
        o1.y = fmaxf(di * acc[5] + b[sub * 8 + 5], 0.0f);
        o1.z = fmaxf(di * acc[6] + b[sub * 8 + 6], 0.0f);
        o1.w = fmaxf(di * acc[7] + b[sub * 8 + 7], 0.0f);
        *(float4*)&xout[(size_t)i * H2 + sub * 8] = o0;
        *(float4*)&xout[(size_t)i * H2 + sub * 8 + 4] = o1;
    }
}

// ---------------------------------------------------------------- classifier + log_softmax
__global__ __launch_bounds__(256) void final_kernel(const float* __restrict__ X2,
                                                    const float* __restrict__ Wc,
                                                    const float* __restrict__ bc,
                                                    float* __restrict__ out) {
    __shared__ float Ws[H2 * NCLS];   // 320 floats > 256 threads: loop
    __shared__ float bs[NCLS];
    for (int idx = threadIdx.x; idx < H2 * NCLS; idx += 256) Ws[idx] = Wc[idx];
    if (threadIdx.x < NCLS) bs[threadIdx.x] = bc[threadIdx.x];
    __syncthreads();
    int i = blockIdx.x * blockDim.x + threadIdx.x;
    if (i >= N_NODES) return;
    float x[H2];
    #pragma unroll
    for (int k = 0; k < H2; ++k) x[k] = X2[(size_t)i * H2 + k];
    float lg[NCLS];
    #pragma unroll
    for (int c = 0; c < NCLS; ++c) {
        float acc = bs[c];
        #pragma unroll
        for (int k = 0; k < H2; ++k) acc += x[k] * Ws[k * NCLS + c];
        lg[c] = acc;
    }
    float m = lg[0];
    #pragma unroll
    for (int c = 1; c < NCLS; ++c) m = fmaxf(m, lg[c]);
    float s = 0.0f;
    #pragma unroll
    for (int c = 0; c < NCLS; ++c) s += expf(lg[c] - m);
    float lse = m + logf(s);
    #pragma unroll
    for (int c = 0; c < NCLS; ++c) out[(size_t)i * NCLS + c] = lg[c] - lse;
}

// ----------------------------------------------------------------
extern "C" void kernel_launch(void* const* d_in, const int* in_sizes, int n_in,
                              void* d_out, int out_size, void* d_ws, size_t ws_size,
                              hipStream_t stream) {
    const float* feature = (const float*)d_in[0];
    const int*   eidx    = (const int*)d_in[1];
    const float* W1      = (const float*)d_in[2];
    const float* b1      = (const float*)d_in[3];
    const float* W2      = (const float*)d_in[4];
    const float* b2      = (const float*)d_in[5];
    const float* Wc      = (const float*)d_in[6];
    const float* bc      = (const float*)d_in[7];
    float* out = (float*)d_out;

    const int E = in_sizes[1] / 2;
    const int* src = eidx;
    const int* dst = eidx + E;

    // workspace layout (4B units):
    //   dinv [N] f32 ; row_start [N], row_end [N] int
    //   gcur [NBUCK*16] + ovcnt [NBUCK*16] (one memset)
    //   ovbuf [NBUCK*OVCAP] ; mainr [NBUCK*MCAP] (dense CSR in place)
    //   h1b [N*64] bf16 (layer 2 overlays h2b [N*32])
    //   x1  [N*64] f32  (layer 2 overlays x2 [N*32])
    float*          ws        = (float*)d_ws;
    float*          dinv      = ws;
    int*            row_start = (int*)(dinv + N_NODES);
    int*            row_end   = row_start + N_NODES;
    unsigned int*   gcur      = (unsigned int*)(row_end + N_NODES);
    unsigned int*   ovcnt     = gcur + (size_t)NBUCK * 16;
    unsigned int*   ovbuf     = ovcnt + (size_t)NBUCK * 16;
    unsigned int*   mainr     = ovbuf + (size_t)NBUCK * OVCAP;
    unsigned short* h1b       = (unsigned short*)(mainr + (size_t)NBUCK * MCAP);
    float*          x1        = (float*)(h1b + (size_t)N_NODES * H1);
    unsigned short* h2b       = h1b;                 // overlay: h1 dead after pull1
    float*          x2        = x1;                  // overlay: x1 dead after gemm2

    // CSR build
    hipMemsetAsync(gcur, 0, (size_t)NBUCK * 32 * sizeof(unsigned int), stream);
    bin_kernel<<<BIN_WG, 512, 0, stream>>>(src, dst, E, gcur, mainr, ovcnt, ovbuf);
    build_kernel<<<NBUCK, 256, 0, stream>>>(gcur, mainr, ovcnt, ovbuf,
                                            dinv, row_start, row_end);

    // layer 1
    gemm1_kernel<<<(N_NODES + 63) / 64, 256, 0, stream>>>(feature, W1, dinv, h1b);
    {
        unsigned int grid = (unsigned int)(((size_t)N_NODES * 64 + 255) / 256);
        pull1_kernel<<<grid, 256, 0, stream>>>(h1b, mainr, row_start, row_end, dinv, b1, x1);
    }

    // layer 2
    gemm2_kernel<<<(N_NODES + 63) / 64, 256, 0, stream>>>(x1, W2, dinv, h2b);
    {
        unsigned int grid = (unsigned int)(((size_t)N_NODES * 64 + 255) / 256);
        pull2_kernel<<<grid, 256, 0, stream>>>(h2b, mainr, row_start, row_end, dinv, b2, x2);
    }

    // classifier + log_softmax
    final_kernel<<<(N_NODES + 255) / 256, 256, 0, stream>>>(x2, Wc, bc, out);
}

// Round 13
// 312.593 us; speedup vs baseline: 1.1553x; 1.0112x over previous
//
#include <hip/hip_runtime.h>

#define N_NODES 100000
#define F_IN 128
#define H1 64
#define H2 32
#define NCLS 10

#define BS_N 256                                   // nodes per bucket
#define NBUCK ((N_NODES + BS_N - 1) / BS_N)        // 391 buckets
#define LCAP 32                                    // LDS slots per bucket
#define MCAP 12288                                 // main entries/bucket incl. sentinel pad
#define OVCAP 2048                                 // hard-overflow entries per bucket (~never used)
#define STCAP 12288                                // build LDS stage
#define BIN_WG 256                                 // bin workgroups (1/CU), 512 thr each
#define SENT 0xFFFFFFFFu                           // sentinel entry (skipped in build)

__device__ __forceinline__ unsigned short f2bf(float f) {   // RNE f32->bf16
    unsigned int u = __float_as_uint(f);
    return (unsigned short)((u + 0x7fffu + ((u >> 16) & 1u)) >> 16);
}
__device__ __forceinline__ float bf2f(unsigned short u) {
    return __uint_as_float((unsigned int)u << 16);
}
// accumulate 2 packed bf16 (one dword) into a[0],a[1] — shift/and only, no cvt
__device__ __forceinline__ void accp(float* a, unsigned int u) {
    a[0] += __uint_as_float(u << 16);
    a[1] += __uint_as_float(u & 0xffff0000u);
}
__device__ __forceinline__ void accp4(float* a, uint4 v) {
    accp(a + 0, v.x); accp(a + 2, v.y); accp(a + 4, v.z); accp(a + 6, v.w);
}

// ---------------------------------------------------------------- pass 1: LDS-staged binning
// Scattered-line-op ceiling (~20-40 ops/ns) -> every global write is a full 64B line.
// E is even (3.2M): thread t owns edge pair (base+2t, base+2t+1) -> int2 loads.
__global__ __launch_bounds__(512) void bin_kernel(const int* __restrict__ src,
                                                  const int* __restrict__ dst, int E,
                                                  unsigned int* __restrict__ gcur,
                                                  unsigned int* __restrict__ mainr,
                                                  unsigned int* __restrict__ ovcnt,
                                                  unsigned int* __restrict__ ovbuf) {
    __shared__ unsigned int buf[NBUCK][LCAP];   // 50.0 KB
    __shared__ int cnt[NBUCK];
    int tid = threadIdx.x;
    for (int b = tid; b < NBUCK; b += 512) cnt[b] = 0;

    int chunk = (E + gridDim.x - 1) / gridDim.x;
    int e_lo = blockIdx.x * chunk;
    int e_hi = min(e_lo + chunk, E);

    int d0 = 0, s0 = 0, d1 = 0, s1 = 0;
    {
        int ea = e_lo + 2 * tid;
        if (ea < e_hi) {
            int2 dd = *(const int2*)&dst[ea];
            int2 ss = *(const int2*)&src[ea];
            d0 = dd.x; s0 = ss.x; d1 = dd.y; s1 = ss.y;
        }
    }
    __syncthreads();

    for (int base = e_lo; base < e_hi; base += 1024) {
        int ea = base + 2 * tid;
        if (ea < e_hi) {
            {
                int b = d0 >> 8;
                unsigned int en = ((unsigned int)s0 << 8) | (unsigned int)(d0 & 255);
                int p = atomicAdd(&cnt[b], 1);
                if (p < LCAP) buf[b][p] = en;
                else {  // hard overflow: ~never
                    unsigned int op = atomicAdd(&ovcnt[b * 16], 1u);
                    if (op < OVCAP) ovbuf[(size_t)b * OVCAP + op] = en;
                }
            }
            if (ea + 1 < e_hi) {
                int b = d1 >> 8;
                unsigned int en = ((unsigned int)s1 << 8) | (unsigned int)(d1 & 255);
                int p = atomicAdd(&cnt[b], 1);
                if (p < LCAP) buf[b][p] = en;
                else {
                    unsigned int op = atomicAdd(&ovcnt[b * 16], 1u);
                    if (op < OVCAP) ovbuf[(size_t)b * OVCAP + op] = en;
                }
            }
        }
        __syncthreads();
        {   // prefetch next batch (in flight across the flush phase)
            int nb = base + 1024 + 2 * tid;
            if (nb < e_hi) {
                int2 dd = *(const int2*)&dst[nb];
                int2 ss = *(const int2*)&src[nb];
                d0 = dd.x; s0 = ss.x; d1 = dd.y; s1 = ss.y;
            }
        }
        for (int b = tid; b < NBUCK; b += 512) {
            int c = cnt[b]; if (c > LCAP) c = LCAP;
            int nf = c & ~15;
            if (nf) {
                unsigned int gb = atomicAdd(&gcur[b * 16], (unsigned int)nf);
                if (gb + (unsigned)nf <= MCAP) {
                    for (int k = 0; k < nf; k += 4) {
                        uint4 v = make_uint4(buf[b][k], buf[b][k + 1],
                                             buf[b][k + 2], buf[b][k + 3]);
                        *(uint4*)&mainr[(size_t)b * MCAP + gb + k] = v;
                    }
                } else {
                    unsigned int op = atomicAdd(&ovcnt[b * 16], (unsigned int)nf);
                    for (int k = 0; k < nf; ++k)
                        if (op + k < OVCAP) ovbuf[(size_t)b * OVCAP + op + k] = buf[b][k];
                }
                int rem = c - nf;
                for (int k = 0; k < rem; ++k) buf[b][k] = buf[b][nf + k];
                cnt[b] = rem;
            } else {
                cnt[b] = c;
            }
        }
        __syncthreads();
    }
    // final flush: pad remainders (<=15) to a full 16-chunk with sentinels -> full-line stores
    for (int b = tid; b < NBUCK; b += 512) {
        int c = cnt[b]; if (c > LCAP) c = LCAP;
        if (c) {
            int cp = (c + 15) & ~15;
            for (int k = c; k < cp; ++k) buf[b][k] = SENT;
            unsigned int gb = atomicAdd(&gcur[b * 16], (unsigned int)cp);
            if (gb + (unsigned)cp <= MCAP) {
                for (int k = 0; k < cp; k += 4) {
                    uint4 v = make_uint4(buf[b][k], buf[b][k + 1],
                                         buf[b][k + 2], buf[b][k + 3]);
                    *(uint4*)&mainr[(size_t)b * MCAP + gb + k] = v;
                }
            } else {
                unsigned int op = atomicAdd(&ovcnt[b * 16], (unsigned int)c);
                for (int k = 0; k < c; ++k)
                    if (op + k < OVCAP) ovbuf[(size_t)b * OVCAP + op + k] = buf[b][k];
            }
        }
    }
}

// ---------------------------------------------------------------- pass 2: per-bucket local CSR build
// 512 threads: stage/histogram/scatter at 2x parallelism; 256-wide scan confined to waves 0-3.
__global__ __launch_bounds__(512) void build_kernel(const unsigned int* __restrict__ gcur,
                                                    unsigned int* __restrict__ mainr,
                                                    const unsigned int* __restrict__ ovcnt,
                                                    const unsigned int* __restrict__ ovbuf,
                                                    float* __restrict__ dinv,
                                                    int* __restrict__ row_start,
                                                    int* __restrict__ row_end) {
    __shared__ unsigned int stage[STCAP];   // 48 KB
    __shared__ int degl[BS_N];
    __shared__ int rs_l[BS_N];
    __shared__ int curl[BS_N];
    __shared__ int wtot[4];
    int b = blockIdx.x;
    int tid = threadIdx.x;

    int cm = (int)gcur[b * 16]; if (cm > MCAP) cm = MCAP;
    for (int i = tid; i < cm; i += 512) stage[i] = mainr[(size_t)b * MCAP + i];
    int co = (int)ovcnt[b * 16]; if (co > OVCAP) co = OVCAP;
    for (int i = tid; i < co; i += 512) {
        int p = cm + i;
        if (p < STCAP) stage[p] = ovbuf[(size_t)b * OVCAP + i];
    }
    int c = cm + co; if (c > STCAP) c = STCAP;
    if (tid < BS_N) degl[tid] = 0;
    __syncthreads();

    for (int i = tid; i < c; i += 512) {
        unsigned int en = stage[i];
        if (en != SENT) atomicAdd(&degl[en & 255], 1);
    }
    __syncthreads();

    if (tid < 256) {   // waves 0-3: exclusive scan over 256 degrees
        int lane = tid & 63, w = tid >> 6;
        int d = degl[tid];
        int x = d;
        #pragma unroll
        for (int off = 1; off < 64; off <<= 1) {
            int y = __shfl_up(x, off);
            if (lane >= off) x += y;
        }
        if (lane == 63) wtot[w] = x;
        __syncthreads();
        int pbase = 0;
        #pragma unroll
        for (int k = 0; k < 4; ++k) if (k < w) pbase += wtot[k];
        rs_l[tid] = pbase + x - d;
        curl[tid] = 0;
    } else {
        __syncthreads();   // matching barrier for waves 4-7
    }
    __syncthreads();

    size_t gbase = (size_t)b * MCAP;
    for (int i = tid; i < c; i += 512) {
        unsigned int en = stage[i];
        if (en != SENT) {
            int dl = en & 255;
            int p = atomicAdd(&curl[dl], 1);
            mainr[gbase + rs_l[dl] + p] = en >> 8;
        }
    }
    if (tid < 256) {
        int node = b * BS_N + tid;
        if (node < N_NODES) {
            int deg = degl[tid];
            dinv[node] = rsqrtf((float)deg + 1.0f);
            row_start[node] = (int)gbase + rs_l[tid];
            row_end[node] = (int)gbase + rs_l[tid] + deg;
        }
    }
}

// ---------------------------------------------------------------- GEMM 1: [N,128]@[128,64] -> bf16, scaled by dinv
__global__ __launch_bounds__(256) void gemm1_kernel(const float* __restrict__ X,
                                                    const float* __restrict__ W,
                                                    const float* __restrict__ dinv,
                                                    unsigned short* __restrict__ H) {
    __shared__ float Xs[64][68];
    __shared__ float Ws[F_IN * H1];
    int r0 = blockIdx.x * 64;
    const float4* W4 = (const float4*)W;
    float4* Ws4 = (float4*)Ws;
    for (int i = threadIdx.x; i < F_IN * H1 / 4; i += 256) Ws4[i] = W4[i];

    int tx = threadIdx.x & 15;
    int ty = threadIdx.x >> 4;
    float acc[4][4] = {};

    for (int kh = 0; kh < 2; ++kh) {
        __syncthreads();
        for (int it = 0; it < 4; ++it) {
            int idx = threadIdx.x + it * 256;
            int r = idx >> 4, k4 = idx & 15;
            int row = r0 + r;
            float4 v = (row < N_NODES)
                ? ((const float4*)X)[(size_t)row * 32 + kh * 16 + k4]
                : make_float4(0.f, 0.f, 0.f, 0.f);
            *(float4*)&Xs[r][k4 * 4] = v;
        }
        __syncthreads();
        #pragma unroll 8
        for (int k = 0; k < 64; ++k) {
            float4 wb = *(const float4*)&Ws[(kh * 64 + k) * H1 + tx * 4];
            float xa0 = Xs[ty * 4 + 0][k];
            float xa1 = Xs[ty * 4 + 1][k];
            float xa2 = Xs[ty * 4 + 2][k];
            float xa3 = Xs[ty * 4 + 3][k];
            acc[0][0] += xa0 * wb.x; acc[0][1] += xa0 * wb.y; acc[0][2] += xa0 * wb.z; acc[0][3] += xa0 * wb.w;
            acc[1][0] += xa1 * wb.x; acc[1][1] += xa1 * wb.y; acc[1][2] += xa1 * wb.z; acc[1][3] += xa1 * wb.w;
            acc[2][0] += xa2 * wb.x; acc[2][1] += xa2 * wb.y; acc[2][2] += xa2 * wb.z; acc[2][3] += xa2 * wb.w;
            acc[3][0] += xa3 * wb.x; acc[3][1] += xa3 * wb.y; acc[3][2] += xa3 * wb.z; acc[3][3] += xa3 * wb.w;
        }
    }
    #pragma unroll
    for (int i = 0; i < 4; ++i) {
        int row = r0 + ty * 4 + i;
        if (row < N_NODES) {
            float dv = dinv[row];
            unsigned int lo = (unsigned int)f2bf(acc[i][0] * dv) |
                              ((unsigned int)f2bf(acc[i][1] * dv) << 16);
            unsigned int hi = (unsigned int)f2bf(acc[i][2] * dv) |
                              ((unsigned int)f2bf(acc[i][3] * dv) << 16);
            *(uint2*)&H[(size_t)row * H1 + tx * 4] = make_uint2(lo, hi);
        }
    }
}

// ---------------------------------------------------------------- GEMM 2: bf16[N,64]@f32[64,32] -> bf16, scaled by dinv
__global__ __launch_bounds__(256) void gemm2_kernel(const unsigned short* __restrict__ X,
                                                    const float* __restrict__ W,
                                                    const float* __restrict__ dinv,
                                                    unsigned short* __restrict__ H) {
    __shared__ float Xs[64][68];
    __shared__ float Ws[H1 * H2];
    int r0 = blockIdx.x * 64;
    const float4* W4 = (const float4*)W;
    float4* Ws4 = (float4*)Ws;
    for (int i = threadIdx.x; i < H1 * H2 / 4; i += 256) Ws4[i] = W4[i];
    // stage bf16 X tile: 64 rows x 8 uint4 (16 bf16 each... 8 bf16/uint4) = 512 uint4
    for (int it = 0; it < 2; ++it) {
        int idx = threadIdx.x + it * 256;
        int r = idx >> 3, k8 = idx & 7;        // k8: group of 8 bf16 features
        int row = r0 + r;
        uint4 v = (row < N_NODES)
            ? ((const uint4*)X)[(size_t)row * 8 + k8]
            : make_uint4(0u, 0u, 0u, 0u);
        float4 a, bb;
        a.x = bf2f((unsigned short)(v.x & 0xffff)); a.y = bf2f((unsigned short)(v.x >> 16));
        a.z = bf2f((unsigned short)(v.y & 0xffff)); a.w = bf2f((unsigned short)(v.y >> 16));
        bb.x = bf2f((unsigned short)(v.z & 0xffff)); bb.y = bf2f((unsigned short)(v.z >> 16));
        bb.z = bf2f((unsigned short)(v.w & 0xffff)); bb.w = bf2f((unsigned short)(v.w >> 16));
        *(float4*)&Xs[r][k8 * 8] = a;
        *(float4*)&Xs[r][k8 * 8 + 4] = bb;
    }
    __syncthreads();
    int tx = threadIdx.x & 15;
    int ty = threadIdx.x >> 4;
    float acc[4][2] = {};
    #pragma unroll 8
    for (int k = 0; k < 64; ++k) {
        float2 wb = *(const float2*)&Ws[k * H2 + tx * 2];
        float xa0 = Xs[ty * 4 + 0][k];
        float xa1 = Xs[ty * 4 + 1][k];
        float xa2 = Xs[ty * 4 + 2][k];
        float xa3 = Xs[ty * 4 + 3][k];
        acc[0][0] += xa0 * wb.x; acc[0][1] += xa0 * wb.y;
        acc[1][0] += xa1 * wb.x; acc[1][1] += xa1 * wb.y;
        acc[2][0] += xa2 * wb.x; acc[2][1] += xa2 * wb.y;
        acc[3][0] += xa3 * wb.x; acc[3][1] += xa3 * wb.y;
    }
    #pragma unroll
    for (int i = 0; i < 4; ++i) {
        int row = r0 + ty * 4 + i;
        if (row < N_NODES) {
            float dv = dinv[row];
            unsigned int v = (unsigned int)f2bf(acc[i][0] * dv) |
                             ((unsigned int)f2bf(acc[i][1] * dv) << 16);
            *(unsigned int*)&H[(size_t)row * H2 + tx * 2] = v;
        }
    }
}

// ---------------------------------------------------------------- pull1: wave/node, 8 lanes/edge, uint4 gathers -> bf16 out
__global__ __launch_bounds__(256) void pull1_kernel(const unsigned short* __restrict__ h,
                                                    const unsigned int* __restrict__ csr,
                                                    const int* __restrict__ row_start,
                                                    const int* __restrict__ row_end,
                                                    const float* __restrict__ dinv,
                                                    const float* __restrict__ b,
                                                    unsigned short* __restrict__ xout) {
    int wave = (blockIdx.x * 256 + threadIdx.x) >> 6;   // grid exact: 25000 blocks
    int lane = threadIdx.x & 63;
    int g = lane >> 3;
    int sub = lane & 7;
    int i = wave;
    int e0 = row_start[i], e1 = row_end[i];
    float acc[8] = {};
    int e = e0;
    for (; e + 16 <= e1; e += 16) {
        int s0 = csr[e + g];
        int s1 = csr[e + 8 + g];
        uint4 v0 = *(const uint4*)&h[(size_t)s0 * H1 + sub * 8];
        uint4 v1 = *(const uint4*)&h[(size_t)s1 * H1 + sub * 8];
        accp4(acc, v0);
        accp4(acc, v1);
    }
    if (e + 8 <= e1) {
        int s = csr[e + g];
        uint4 v = *(const uint4*)&h[(size_t)s * H1 + sub * 8];
        accp4(acc, v);
        e += 8;
    }
    if (e < e1) {
        int idx = e + g;
        if (idx < e1) {
            int s = csr[idx];
            uint4 v = *(const uint4*)&h[(size_t)s * H1 + sub * 8];
            accp4(acc, v);
        }
    }
    #pragma unroll
    for (int m = 8; m < 64; m <<= 1) {
        #pragma unroll
        for (int j = 0; j < 8; ++j) acc[j] += __shfl_xor(acc[j], m);
    }
    if (g == 0) {
        float di = dinv[i];
        uint4 sv = *(const uint4*)&h[(size_t)i * H1 + sub * 8];   // self loop
        accp4(acc, sv);
        float o[8];
        #pragma unroll
        for (int j = 0; j < 8; ++j)
            o[j] = fmaxf(di * acc[j] + b[sub * 8 + j], 0.0f);
        uint4 pk;
        pk.x = (unsigned int)f2bf(o[0]) | ((unsigned int)f2bf(o[1]) << 16);
        pk.y = (unsigned int)f2bf(o[2]) | ((unsigned int)f2bf(o[3]) << 16);
        pk.z = (unsigned int)f2bf(o[4]) | ((unsigned int)f2bf(o[5]) << 16);
        pk.w = (unsigned int)f2bf(o[6]) | ((unsigned int)f2bf(o[7]) << 16);
        *(uint4*)&xout[(size_t)i * H1 + sub * 8] = pk;
    }
}

// ---------------------------------------------------------------- pull2: wave/node, 4 lanes/edge, uint4 gathers
__global__ __launch_bounds__(256) void pull2_kernel(const unsigned short* __restrict__ h,
                                                    const unsigned int* __restrict__ csr,
                                                    const int* __restrict__ row_start,
                                                    const int* __restrict__ row_end,
                                                    const float* __restrict__ dinv,
                                                    const float* __restrict__ b,
                                                    float* __restrict__ xout) {
    int wave = (blockIdx.x * 256 + threadIdx.x) >> 6;
    int lane = threadIdx.x & 63;
    int g = lane >> 2;
    int sub = lane & 3;
    int i = wave;
    int e0 = row_start[i], e1 = row_end[i];
    float acc[8] = {};
    int e = e0;
    for (; e + 32 <= e1; e += 32) {
        int s0 = csr[e + g];
        int s1 = csr[e + 16 + g];
        uint4 v0 = *(const uint4*)&h[(size_t)s0 * H2 + sub * 8];
        uint4 v1 = *(const uint4*)&h[(size_t)s1 * H2 + sub * 8];
        accp4(acc, v0);
        accp4(acc, v1);
    }
    if (e + 16 <= e1) {
        int s = csr[e + g];
        uint4 v = *(const uint4*)&h[(size_t)s * H2 + sub * 8];
        accp4(acc, v);
        e += 16;
    }
    if (e < e1) {
        int idx = e + g;
        if (idx < e1) {
            int s = csr[idx];
            uint4 v = *(const uint4*)&h[(size_t)s * H2 + sub * 8];
            accp4(acc, v);
        }
    }
    #pragma unroll
    for (int m = 4; m < 64; m <<= 1) {
        #pragma unroll
        for (int j = 0; j < 8; ++j) acc[j] += __shfl_xor(acc[j], m);
    }
    if (g == 0) {
        float di = dinv[i];
        uint4 sv = *(const uint4*)&h[(size_t)i * H2 + sub * 8];   // self loop
        accp4(acc, sv);
        float4 o0, o1;
        o0.x = fmaxf(di * acc[0] + b[sub * 8 + 0], 0.0f);
        o0.y = fmaxf(di * acc[1] + b[sub * 8 + 1], 0.0f);
        o0.z = fmaxf(di * acc[2] + b[sub * 8 + 2], 0.0f);
        o0.w = fmaxf(di * acc[3] + b[sub * 8 + 3], 0.0f);
        o1.x = fmaxf(di * acc[4] + b[sub * 8 + 4], 0.0f);
        o1.y = fmaxf(di * acc[5] + b[sub * 8 + 5], 0.0f);
        o1.z = fmaxf(di * acc[6] + b[sub * 8 + 6], 0.0f);
        o1.w = fmaxf(di * acc[7] + b[sub * 8 + 7], 0.0f);
        *(float4*)&xout[(size_t)i * H2 + sub * 8] = o0;
        *(float4*)&xout[(size_t)i * H2 + sub * 8 + 4] = o1;
    }
}

// ---------------------------------------------------------------- classifier + log_softmax
__global__ __launch_bounds__(256) void final_kernel(const float* __restrict__ X2,
                                                    const float* __restrict__ Wc,
                                                    const float* __restrict__ bc,
                                                    float* __restrict__ out) {
    __shared__ float Ws[H2 * NCLS];   // 320 floats > 256 threads: loop
    __shared__ float bs[NCLS];
    for (int idx = threadIdx.x; idx < H2 * NCLS; idx += 256) Ws[idx] = Wc[idx];
    if (threadIdx.x < NCLS) bs[threadIdx.x] = bc[threadIdx.x];
    __syncthreads();
    int i = blockIdx.x * blockDim.x + threadIdx.x;
    if (i >= N_NODES) return;
    float x[H2];
    #pragma unroll
    for (int k = 0; k < H2; ++k) x[k] = X2[(size_t)i * H2 + k];
    float lg[NCLS];
    #pragma unroll
    for (int c = 0; c < NCLS; ++c) {
        float acc = bs[c];
        #pragma unroll
        for (int k = 0; k < H2; ++k) acc += x[k] * Ws[k * NCLS + c];
        lg[c] = acc;
    }
    float m = lg[0];
    #pragma unroll
    for (int c = 1; c < NCLS; ++c) m = fmaxf(m, lg[c]);
    float s = 0.0f;
    #pragma unroll
    for (int c = 0; c < NCLS; ++c) s += expf(lg[c] - m);
    float lse = m + logf(s);
    #pragma unroll
    for (int c = 0; c < NCLS; ++c) out[(size_t)i * NCLS + c] = lg[c] - lse;
}

// ----------------------------------------------------------------
extern "C" void kernel_launch(void* const* d_in, const int* in_sizes, int n_in,
                              void* d_out, int out_size, void* d_ws, size_t ws_size,
                              hipStream_t stream) {
    const float* feature = (const float*)d_in[0];
    const int*   eidx    = (const int*)d_in[1];
    const float* W1      = (const float*)d_in[2];
    const float* b1      = (const float*)d_in[3];
    const float* W2      = (const float*)d_in[4];
    const float* b2      = (const float*)d_in[5];
    const float* Wc      = (const float*)d_in[6];
    const float* bc      = (const float*)d_in[7];
    float* out = (float*)d_out;

    const int E = in_sizes[1] / 2;
    const int* src = eidx;
    const int* dst = eidx + E;

    // workspace layout (4B units):
    //   dinv [N] f32 ; row_start [N], row_end [N] int
    //   gcur [NBUCK*16] + ovcnt [NBUCK*16] (one memset)
    //   ovbuf [NBUCK*OVCAP] ; mainr [NBUCK*MCAP] (dense CSR in place)
    //   region A: h1b [N*64] bf16 (12.8 MB; layer 2 overlays h2b [N*32])
    //   region B: x1b [N*64] bf16 (12.8 MB; x2 f32 [N*32] overlays after gemm2)
    float*          ws        = (float*)d_ws;
    float*          dinv      = ws;
    int*            row_start = (int*)(dinv + N_NODES);
    int*            row_end   = row_start + N_NODES;
    unsigned int*   gcur      = (unsigned int*)(row_end + N_NODES);
    unsigned int*   ovcnt     = gcur + (size_t)NBUCK * 16;
    unsigned int*   ovbuf     = ovcnt + (size_t)NBUCK * 16;
    unsigned int*   mainr     = ovbuf + (size_t)NBUCK * OVCAP;
    unsigned short* h1b       = (unsigned short*)(mainr + (size_t)NBUCK * MCAP);
    unsigned short* x1b       = h1b + (size_t)N_NODES * H1;
    unsigned short* h2b       = h1b;                 // overlay A: h1 dead after pull1
    float*          x2        = (float*)x1b;         // overlay B: x1b dead after gemm2

    // CSR build
    hipMemsetAsync(gcur, 0, (size_t)NBUCK * 32 * sizeof(unsigned int), stream);
    bin_kernel<<<BIN_WG, 512, 0, stream>>>(src, dst, E, gcur, mainr, ovcnt, ovbuf);
    build_kernel<<<NBUCK, 512, 0, stream>>>(gcur, mainr, ovcnt, ovbuf,
                                            dinv, row_start, row_end);

    // layer 1
    gemm1_kernel<<<(N_NODES + 63) / 64, 256, 0, stream>>>(feature, W1, dinv, h1b);
    {
        unsigned int grid = (unsigned int)(((size_t)N_NODES * 64 + 255) / 256);
        pull1_kernel<<<grid, 256, 0, stream>>>(h1b, mainr, row_start, row_end, dinv, b1, x1b);
    }

    // layer 2
    gemm2_kernel<<<(N_NODES + 63) / 64, 256, 0, stream>>>(x1b, W2, dinv, h2b);
    {
        unsigned int grid = (unsigned int)(((size_t)N_NODES * 64 + 255) / 256);
        pull2_kernel<<<grid, 256, 0, stream>>>(h2b, mainr, row_start, row_end, dinv, b2, x2);
    }

    // classifier + log_softmax
    final_kernel<<<(N_NODES + 255) / 256, 256, 0, stream>>>(x2, Wc, bc, out);
}